// Round 4
// baseline (354.925 us; speedup 1.0000x reference)
//
#include <hip/hip_runtime.h>

#define BATCH 16384
#define DIM 128
#define NLINK 500
#define EHALF 64          // e-split: 2 blocks per link
#define DP_STRIDE 132     // padded dp/dn row stride (128+4) — de-conflicts group broadcasts
#define CAPW 64           // per-wave sub-bucket capacity (Binomial(4096,1/500), mean 8.2)

// d_ws float layout: p0, p1, n0, n1 — BATCH each, every slot written exactly once.
#define WS_P0 0
#define WS_P1 BATCH
#define WS_N0 (2 * BATCH)
#define WS_N1 (3 * BATCH)

typedef __attribute__((address_space(1))) const unsigned int ga_u32;
typedef __attribute__((address_space(3))) unsigned int ls_u32;

// One block per (link, e-half). Each wave: (a) issues async global->LDS staging of
// its share of the 32 KB M-half, (b) scans its 4096-entry quarter of r with
// ballot/popcount building a private sub-bucket (no atomics, no barriers),
// (c) after ONE barrier, processes its sub-bucket 4 samples/round with zero
// further synchronization (dp/dn rows are private to each 16-lane group).
__global__ __launch_bounds__(256, 3) void k_main(
    const float* __restrict__ node_w, const float* __restrict__ link_w,
    const float* __restrict__ transfer_w,
    const int* __restrict__ sp, const int* __restrict__ tp,
    const int* __restrict__ sn, const int* __restrict__ tn,
    const int* __restrict__ r, float* __restrict__ wsf)
{
    __shared__ float Ms[DIM * EHALF];        // 32 KB: rows d, cols e-local
    __shared__ float dp[16 * DP_STRIDE];     // 8.25 KB
    __shared__ float dn[16 * DP_STRIDE];     // 8.25 KB
    __shared__ float remb[EHALF];            // 256 B
    __shared__ int lbucket[4 * CAPW];        // 1 KB: per-wave sub-buckets

    const int link = blockIdx.x >> 1;
    const int h = blockIdx.x & 1;
    const int t = threadIdx.x;
    const int w = t >> 6;        // wave 0..3
    const int lane = t & 63;

    // --- (a) async M staging: 8 x 16B per thread; LDS dest is uniform+lane*16.
    {
        const float4* gbase = (const float4*)transfer_w + (size_t)link * 4096 + h * 16;
        #pragma unroll
        for (int i = 0; i < 8; i++) {
            int c = t + 256 * i;                        // float4 index in Ms
            const float4* gp = gbase + (c >> 4) * 32 + (c & 15);
            __builtin_amdgcn_global_load_lds((ga_u32*)gp, (ls_u32*)(Ms + 4 * c), 16, 0, 0);
        }
    }
    if (t < 16)
        ((float4*)remb)[t] = ((const float4*)(link_w + link * DIM + h * EHALF))[t];

    // --- (b) per-wave ballot scan of r quarter (overlaps M staging latency)
    int cw = 0;
    {
        const int4* r4 = (const int4*)r;
        int* myb = lbucket + w * CAPW;
        const unsigned long long ltmask = (lane == 63) ? ~0ull >> 1
                                                       : (1ull << lane) - 1;
        #pragma unroll 4
        for (int it = 0; it < 16; it++) {
            int gi = w * 1024 + it * 64 + lane;         // int4 index into r
            int4 v = r4[gi];
            int base4 = gi * 4;
            unsigned long long m;
            m = __ballot(v.x == link);
            if (v.x == link) myb[cw + __popcll(m & ltmask)] = base4 + 0;
            cw += __popcll(m);
            m = __ballot(v.y == link);
            if (v.y == link) myb[cw + __popcll(m & ltmask)] = base4 + 1;
            cw += __popcll(m);
            m = __ballot(v.z == link);
            if (v.z == link) myb[cw + __popcll(m & ltmask)] = base4 + 2;
            cw += __popcll(m);
            m = __ballot(v.w == link);
            if (v.w == link) myb[cw + __popcll(m & ltmask)] = base4 + 3;
            cw += __popcll(m);
        }
    }

    __syncthreads();   // the ONLY barrier: drains M staging; remb visible.

    // --- (c) sample loop: 4 samples/wave/round, no synchronization.
    const int g16 = lane >> 4;           // group within wave 0..3
    const int q = lane & 15;             // e-local quad: e = 4q..4q+3
    float* dpr = dp + (w * 4 + g16) * DP_STRIDE;
    float* dnr = dn + (w * 4 + g16) * DP_STRIDE;
    float* pOut = wsf + (h ? WS_P1 : WS_P0);
    float* nOut = wsf + (h ? WS_N1 : WS_N0);
    const int* myb = lbucket + w * CAPW;

    for (int k = 0; k < cw; k += 4) {
        const int myk = k + g16;
        const bool active = (myk < cw);
        int b = 0;
        if (active) {
            b = myb[myk];
            const float4* a  = (const float4*)(node_w + (size_t)sp[b] * DIM);
            const float4* c2 = (const float4*)(node_w + (size_t)tp[b] * DIM);
            float4 a0 = a[q], a1 = a[q + 16], c0 = c2[q], c1 = c2[q + 16];
            float4 w0, w1;
            w0.x = a0.x - c0.x; w0.y = a0.y - c0.y; w0.z = a0.z - c0.z; w0.w = a0.w - c0.w;
            w1.x = a1.x - c1.x; w1.y = a1.y - c1.y; w1.z = a1.z - c1.z; w1.w = a1.w - c1.w;
            ((float4*)dpr)[q] = w0;
            ((float4*)dpr)[q + 16] = w1;
            const float4* e2 = (const float4*)(node_w + (size_t)sn[b] * DIM);
            const float4* f2 = (const float4*)(node_w + (size_t)tn[b] * DIM);
            float4 e0 = e2[q], e1 = e2[q + 16], f0 = f2[q], f1 = f2[q + 16];
            w0.x = e0.x - f0.x; w0.y = e0.y - f0.y; w0.z = e0.z - f0.z; w0.w = e0.w - f0.w;
            w1.x = e1.x - f1.x; w1.y = e1.y - f1.y; w1.z = e1.z - f1.z; w1.w = e1.w - f1.w;
            ((float4*)dnr)[q] = w0;
            ((float4*)dnr)[q + 16] = w1;
        }
        // no barrier: dpr/dnr rows are written+read by this 16-lane group only.

        float4 accp = {0.f, 0.f, 0.f, 0.f};
        float4 accn = {0.f, 0.f, 0.f, 0.f};
        const float4* M4 = (const float4*)Ms;
        #pragma unroll 4
        for (int d4 = 0; d4 < 32; d4++) {
            float4 vp = ((const float4*)dpr)[d4];   // 16-lane broadcast
            float4 vn = ((const float4*)dnr)[d4];
            float4 m0 = M4[(4 * d4 + 0) * 16 + q];
            float4 m1 = M4[(4 * d4 + 1) * 16 + q];
            float4 m2 = M4[(4 * d4 + 2) * 16 + q];
            float4 m3 = M4[(4 * d4 + 3) * 16 + q];
            accp.x = fmaf(m0.x, vp.x, accp.x); accp.y = fmaf(m0.y, vp.x, accp.y);
            accp.z = fmaf(m0.z, vp.x, accp.z); accp.w = fmaf(m0.w, vp.x, accp.w);
            accn.x = fmaf(m0.x, vn.x, accn.x); accn.y = fmaf(m0.y, vn.x, accn.y);
            accn.z = fmaf(m0.z, vn.x, accn.z); accn.w = fmaf(m0.w, vn.x, accn.w);
            accp.x = fmaf(m1.x, vp.y, accp.x); accp.y = fmaf(m1.y, vp.y, accp.y);
            accp.z = fmaf(m1.z, vp.y, accp.z); accp.w = fmaf(m1.w, vp.y, accp.w);
            accn.x = fmaf(m1.x, vn.y, accn.x); accn.y = fmaf(m1.y, vn.y, accn.y);
            accn.z = fmaf(m1.z, vn.y, accn.z); accn.w = fmaf(m1.w, vn.y, accn.w);
            accp.x = fmaf(m2.x, vp.z, accp.x); accp.y = fmaf(m2.y, vp.z, accp.y);
            accp.z = fmaf(m2.z, vp.z, accp.z); accp.w = fmaf(m2.w, vp.z, accp.w);
            accn.x = fmaf(m2.x, vn.z, accn.x); accn.y = fmaf(m2.y, vn.z, accn.y);
            accn.z = fmaf(m2.z, vn.z, accn.z); accn.w = fmaf(m2.w, vn.z, accn.w);
            accp.x = fmaf(m3.x, vp.w, accp.x); accp.y = fmaf(m3.y, vp.w, accp.y);
            accp.z = fmaf(m3.z, vp.w, accp.z); accp.w = fmaf(m3.w, vp.w, accp.w);
            accn.x = fmaf(m3.x, vn.w, accn.x); accn.y = fmaf(m3.y, vn.w, accn.y);
            accn.z = fmaf(m3.z, vn.w, accn.z); accn.w = fmaf(m3.w, vn.w, accn.w);
        }

        float4 re = ((const float4*)remb)[q];
        float lp = fabsf(accp.x + re.x) + fabsf(accp.y + re.y) +
                   fabsf(accp.z + re.z) + fabsf(accp.w + re.w);
        float ln = fabsf(accn.x + re.x) + fabsf(accn.y + re.y) +
                   fabsf(accn.z + re.z) + fabsf(accn.w + re.w);
        #pragma unroll
        for (int o = 8; o >= 1; o >>= 1) {
            lp += __shfl_xor(lp, o, 16);
            ln += __shfl_xor(ln, o, 16);
        }
        if (active && q == 0) {
            pOut[b] = lp;       // each slot written by exactly one thread chip-wide
            nOut[b] = ln;
        }
    }
}

// Single block: deterministic tree sum, writes out[0] directly (no atomic/zero).
__global__ __launch_bounds__(1024) void k_final(
    const float* __restrict__ wsf, float* __restrict__ out)
{
    __shared__ float wred[16];
    const int t = threadIdx.x;
    const float* p0 = wsf + WS_P0;
    const float* p1 = wsf + WS_P1;
    const float* n0 = wsf + WS_N0;
    const float* n1 = wsf + WS_N1;
    float s = 0.0f;
    #pragma unroll
    for (int m = 0; m < BATCH / 1024; m++) {
        int i = t + 1024 * m;
        float pos = p0[i] + p1[i];
        float neg = n0[i] + n1[i];
        s += fmaxf(pos - neg + 1.0f, 0.0f);
    }
    #pragma unroll
    for (int o = 32; o >= 1; o >>= 1) s += __shfl_xor(s, o, 64);
    if ((t & 63) == 0) wred[t >> 6] = s;
    __syncthreads();
    if (t == 0) {
        float tot = 0.0f;
        #pragma unroll
        for (int i = 0; i < 16; i++) tot += wred[i];
        out[0] = tot * (1.0f / BATCH);
    }
}

extern "C" void kernel_launch(void* const* d_in, const int* in_sizes, int n_in,
                              void* d_out, int out_size, void* d_ws, size_t ws_size,
                              hipStream_t stream) {
    const float* node_w     = (const float*)d_in[0];
    const float* link_w     = (const float*)d_in[1];
    const float* transfer_w = (const float*)d_in[2];
    const int* sp = (const int*)d_in[3];
    const int* tp = (const int*)d_in[4];
    const int* sn = (const int*)d_in[5];
    const int* tn = (const int*)d_in[6];
    const int* r  = (const int*)d_in[7];
    float* out = (float*)d_out;
    float* wsf = (float*)d_ws;

    k_main<<<NLINK * 2, 256, 0, stream>>>(node_w, link_w, transfer_w,
                                          sp, tp, sn, tn, r, wsf);
    k_final<<<1, 1024, 0, stream>>>(wsf, out);
}